// Round 2
// 101.877 us; speedup vs baseline: 1.0179x; 1.0179x over previous
//
#include <hip/hip_runtime.h>
#include <hip/hip_cooperative_groups.h>

namespace cg = cooperative_groups;

#define BB 16
#define LL 1444
#define DD 128
#define CC 21
#define CH 38   // chunk length
#define NK 38   // number of chunks; CH*NK == LL
#define RH 19   // row-half of a chunk
#define KK (CH + 2*CC)   // 80: [v(38) | pre0(21) | tot(21)]

#define CS_ELEMS ((size_t)BB*NK*CC*DD)

#define ASG __attribute__((address_space(1)))
#define ASL __attribute__((address_space(3)))

static __device__ __forceinline__ void gll16(const float* g, float* l) {
  __builtin_amdgcn_global_load_lds((const ASG void*)g, (ASL void*)l, 16, 0, 0);
}
static __device__ __forceinline__ void gll4(const float* g, float* l) {
  __builtin_amdgcn_global_load_lds((const ASG void*)g, (ASL void*)l, 4, 0, 0);
}

// One dense fp32 rank-1 update: acc[0..18] += G[:,k] * x.
// G row addresses are wave-uniform (broadcast LDS reads, conflict-free).
#define GEMM_BODY_X(kv, xv)                                             \
  {                                                                     \
    float x = (xv);                                                     \
    const float4* gp = (const float4*)(Gh + (kv) * 20);                 \
    float4 g0 = gp[0], g1 = gp[1], g2 = gp[2], g3 = gp[3], g4 = gp[4];  \
    acc[0]  += g0.x * x; acc[1]  += g0.y * x; acc[2]  += g0.z * x;      \
    acc[3]  += g0.w * x; acc[4]  += g1.x * x; acc[5]  += g1.y * x;      \
    acc[6]  += g1.z * x; acc[7]  += g1.w * x; acc[8]  += g2.x * x;      \
    acc[9]  += g2.y * x; acc[10] += g2.z * x; acc[11] += g2.w * x;      \
    acc[12] += g3.x * x; acc[13] += g3.y * x; acc[14] += g3.z * x;      \
    acc[15] += g3.w * x; acc[16] += g4.x * x; acc[17] += g4.y * x;      \
    acc[18] += g4.z * x;                                                \
  }

// ---------------- cooperative single-kernel path ----------------
// 608 blocks x 128 threads. LDS = 19456 + 2*6400 = 32256 B ->
// 4 blocks/CU by LDS; launch_bounds(128,2) caps VGPR at 256 ->
// occupancy 4 blocks/CU guaranteed -> 1024 >= 608 co-resident. 
__global__ __launch_bounds__(128, 2) void fused_all(
    const float* __restrict__ src, const int* __restrict__ idx,
    const float* __restrict__ P, float* __restrict__ cs,
    float* __restrict__ tot, float* __restrict__ out,
    float* __restrict__ src_copy)
{
  __shared__ __align__(16) float X[CH][DD];    // 19456 B, lives ph1 -> ph3
  __shared__ __align__(16) float GA[KK][20];   // rows t=0..18 (+pad)
  __shared__ __align__(16) float GB[KK][20];   // rows t=19..37 (+pad)

  cg::grid_group grid = cg::this_grid();

  int tid = threadIdx.x;
  int w = tid >> 6, lane = tid & 63;
  int b = blockIdx.x / NK, kc = blockIdx.x % NK;
  int i0 = kc * CH;
  const float* sc = src + (size_t)(b * LL + i0) * DD;

  // ---- phase 1: async-stage src chunk (19 x 1024B issues over 2 waves) ----
  for (int i = w; i < 19; i += 2)
    gll16(sc + i * 256 + lane * 4, &X[0][0] + i * 256);
  __syncthreads();

  const int* gidx = idx + b * LL + i0;   // uniform address -> s_load

  // per-class chunk sums: each thread owns one d, all 21 classes.
  // (ct==j) is a scalar cmp/cselect -> mask lives in SGPR, FMA on VALU.
  {
    int d = tid;
    float a1[CC];
#pragma unroll
    for (int j = 0; j < CC; ++j) a1[j] = 0.f;
#pragma unroll
    for (int t = 0; t < CH; ++t) {
      int ct = gidx[t];
      float v = X[t][d];
#pragma unroll
      for (int j = 0; j < CC; ++j) {
        float m = (ct == j) ? 1.0f : 0.0f;
        a1[j] += m * v;
      }
    }
    float* co = cs + ((size_t)(b * NK + kc) * CC) * DD + d;
#pragma unroll
    for (int j = 0; j < CC; ++j) co[(size_t)j * DD] = a1[j];
  }

  // src passthrough straight out of LDS
  {
    const float4* v4 = (const float4*)&X[0][0];
    float4* o4 = (float4*)(src_copy + (size_t)(b * LL + i0) * DD);
    for (int i = tid; i < CH * DD / 4; i += 128) o4[i] = v4[i];
  }

  // G build (depends only on idx/P, not cs)
  for (int e = tid; e < 2 * KK * 20; e += 128) {
    int h = e / (KK * 20);
    int rem = e - h * (KK * 20);
    int k = rem / 20, j = rem - k * 20;
    int t = h * RH + j;
    float val = 0.f;
    if (j < RH) {
      int ct = gidx[t];
      if (k < CH) {
        if (k < t) { int ck = gidx[k]; val = P[ct * CC + ck] - P[ck * CC + ct]; }
        else if (k == t) val = (ct != 0 ? 1.0f : 0.0f) - P[ct * CC + ct];
      } else if (k < CH + CC) {
        int c = k - CH; val = P[ct * CC + c] - P[c * CC + ct];
      } else {
        int c = k - CH - CC; val = P[c * CC + ct];
      }
    }
    (h ? &GB[0][0] : &GA[0][0])[k * 20 + j] = val;
  }

  __threadfence();   // device-scope release of cs (cross-XCD readers)
  grid.sync();
  __threadfence();   // acquire side, belt-and-braces

  // ---- phase 2: exclusive scan over NK chunks per (b,c), blocks 0..335 ----
  if (blockIdx.x < BB * CC) {
    int b2 = blockIdx.x / CC, c2 = blockIdx.x % CC;
    float* base = cs + ((size_t)(b2 * NK) * CC + c2) * DD + tid;
    const int S = CC * DD;
    float a[RH];
    float run = 0.f;
#pragma unroll
    for (int i = 0; i < RH; ++i) a[i] = base[(size_t)i * S];
#pragma unroll
    for (int i = 0; i < RH; ++i) { float t = a[i]; base[(size_t)i * S] = run; run += t; }
#pragma unroll
    for (int i = 0; i < RH; ++i) a[i] = base[(size_t)(RH + i) * S];
#pragma unroll
    for (int i = 0; i < RH; ++i) { float t = a[i]; base[(size_t)(RH + i) * S] = run; run += t; }
    tot[((size_t)(b2 * CC + c2)) * DD + tid] = run;
  }

  __threadfence();
  grid.sync();
  __threadfence();

  // ---- phase 3: pre0/tot into registers (shared across both row-halves),
  //               GEMM from the still-resident X ----
  {
    int d = tid;
    const float* pc = cs + ((size_t)(b * NK + kc) * CC) * DD + d;
    const float* tb = tot + ((size_t)b * CC) * DD + d;
    float pr[CC], tr[CC];
#pragma unroll
    for (int c = 0; c < CC; ++c) pr[c] = pc[(size_t)c * DD];
#pragma unroll
    for (int c = 0; c < CC; ++c) tr[c] = tb[(size_t)c * DD];

#define HALF_ROWS(rwc, GH, KEND)                                        \
    {                                                                   \
      const float* Gh = &GH[0][0];                                      \
      float acc[RH];                                                    \
      _Pragma("unroll")                                                 \
      for (int j = 0; j < RH; ++j) acc[j] = 0.f;                        \
      for (int k = 0; k < (KEND); ++k) GEMM_BODY_X(k, X[k][d])          \
      _Pragma("unroll")                                                 \
      for (int c = 0; c < CC; ++c) GEMM_BODY_X(CH + c, pr[c])           \
      _Pragma("unroll")                                                 \
      for (int c = 0; c < CC; ++c) GEMM_BODY_X(CH + CC + c, tr[c])      \
      float* op = out + (size_t)(b * LL + i0 + (rwc) * RH) * DD + d;    \
      _Pragma("unroll")                                                 \
      for (int j = 0; j < RH; ++j) op[(size_t)j * DD] = acc[j];         \
    }

    HALF_ROWS(0, GA, RH)   // rows 0..18 need k <= 18 in the v-part
    HALF_ROWS(1, GB, CH)   // rows 19..37 need k <= 37
#undef HALF_ROWS
  }
}

// ---------------- fallback 3-kernel path (round-0 verified) ----------------
__global__ __launch_bounds__(256) void k1_chunk_sums(
    const float* __restrict__ src, const int* __restrict__ idx,
    float* __restrict__ cs, float* __restrict__ src_copy)
{
  __shared__ __align__(16) float Vs[CH][DD];
  int tid = threadIdx.x;
  int w = tid >> 6, lane = tid & 63;
  int b = blockIdx.x / NK, kc = blockIdx.x % NK;
  int i0 = kc * CH;
  const float* sc = src + (size_t)(b * LL + i0) * DD;

  for (int i = w; i < 19; i += 4)
    gll16(sc + i * 256 + lane * 4, &Vs[0][0] + i * 256);
  __syncthreads();

  const int* gidx = idx + b * LL + i0;
  int d = tid & 127;
  int c0 = (tid >> 7) * 10;
  float acc[11];
#pragma unroll
  for (int j = 0; j < 11; ++j) acc[j] = 0.f;

#pragma unroll
  for (int t = 0; t < CH; ++t) {
    int ct = gidx[t];
    float v = Vs[t][d];
#pragma unroll
    for (int j = 0; j < 11; ++j) {
      float m = (ct == c0 + j) ? 1.0f : 0.0f;
      acc[j] += m * v;
    }
  }

  float* co = cs + ((size_t)(b * NK + kc) * CC) * DD + d;
#pragma unroll
  for (int j = 0; j < 11; ++j) co[(c0 + j) * DD] = acc[j];

  const float4* v4 = (const float4*)&Vs[0][0];
  float4* o4 = (float4*)(src_copy + (size_t)(b * LL + i0) * DD);
  for (int i = tid; i < CH * DD / 4; i += 256) o4[i] = v4[i];
}

__global__ __launch_bounds__(128) void k2_scan(
    float* __restrict__ cs, float* __restrict__ tot)
{
  int b = blockIdx.x / CC, c = blockIdx.x % CC;
  int d = threadIdx.x;
  float* base = cs + ((size_t)(b * NK) * CC + c) * DD + d;
  const int S = CC * DD;
  float a[RH];
  float run = 0.f;
#pragma unroll
  for (int i = 0; i < RH; ++i) a[i] = base[(size_t)i * S];
#pragma unroll
  for (int i = 0; i < RH; ++i) { float t = a[i]; base[(size_t)i * S] = run; run += t; }
#pragma unroll
  for (int i = 0; i < RH; ++i) a[i] = base[(size_t)(RH + i) * S];
#pragma unroll
  for (int i = 0; i < RH; ++i) { float t = a[i]; base[(size_t)(RH + i) * S] = run; run += t; }
  tot[((size_t)(b * CC + c)) * DD + d] = run;
}

__global__ __launch_bounds__(256) void k4_fused(
    const float* __restrict__ src, const int* __restrict__ idx,
    const float* __restrict__ P, const float* __restrict__ cs,
    const float* __restrict__ tot, float* __restrict__ out)
{
  __shared__ __align__(16) float X[KK][DD];
  __shared__ __align__(16) float GA[KK][20];
  __shared__ __align__(16) float GB[KK][20];

  int tid = threadIdx.x;
  int w = tid >> 6, lane = tid & 63;
  int b = blockIdx.x / NK, kc = blockIdx.x % NK;
  int i0 = kc * CH;

  const float* sc = src + (size_t)(b * LL + i0) * DD;
  const float* pc = cs + ((size_t)(b * NK + kc) * CC) * DD;
  const float* tb = tot + (size_t)b * CC * DD;
  float* xf = &X[0][0];

  for (int i = w; i < 19; i += 4) gll16(sc + i * 256 + lane * 4, xf + i * 256);
  for (int i = w; i < 10; i += 4) gll16(pc + i * 256 + lane * 4, xf + CH * DD + i * 256);
  for (int i = w; i < 10; i += 4) gll16(tb + i * 256 + lane * 4, xf + (CH + CC) * DD + i * 256);
  if (w < 2) gll4(pc + 2560 + w * 64 + lane, xf + CH * DD + 2560 + w * 64);
  else       gll4(tb + 2560 + (w - 2) * 64 + lane, xf + (CH + CC) * DD + 2560 + (w - 2) * 64);

  const int* gidx = idx + b * LL + i0;
  for (int e = tid; e < 2 * KK * 20; e += 256) {
    int h = e / (KK * 20);
    int rem = e - h * (KK * 20);
    int k = rem / 20, j = rem - k * 20;
    int t = h * RH + j;
    float val = 0.f;
    if (j < RH) {
      int ct = gidx[t];
      if (k < CH) {
        if (k < t) { int ck = gidx[k]; val = P[ct * CC + ck] - P[ck * CC + ct]; }
        else if (k == t) val = (ct != 0 ? 1.0f : 0.0f) - P[ct * CC + ct];
      } else if (k < CH + CC) {
        int c = k - CH; val = P[ct * CC + c] - P[c * CC + ct];
      } else {
        int c = k - CH - CC; val = P[c * CC + ct];
      }
    }
    (h ? &GB[0][0] : &GA[0][0])[k * 20 + j] = val;
  }
  __syncthreads();

  int rw = __builtin_amdgcn_readfirstlane(w >> 1);
  int dh = w & 1;
  int d = dh * 64 + lane;
  const float* Gh = rw ? &GB[0][0] : &GA[0][0];

  float acc[RH];
#pragma unroll
  for (int j = 0; j < RH; ++j) acc[j] = 0.f;

  int kend1 = __builtin_amdgcn_readfirstlane(rw ? CH : RH);
  for (int k = 0; k < kend1; ++k) GEMM_BODY_X(k, X[k][d])
  for (int k = CH; k < KK; ++k)   GEMM_BODY_X(k, X[k][d])

  float* op = out + (size_t)(b * LL + i0 + rw * RH) * DD + d;
#pragma unroll
  for (int j = 0; j < RH; ++j) op[(size_t)j * DD] = acc[j];
}

extern "C" void kernel_launch(void* const* d_in, const int* in_sizes, int n_in,
                              void* d_out, int out_size, void* d_ws, size_t ws_size,
                              hipStream_t stream) {
  const float* P   = (const float*)d_in[0];   // cls_r_prob (C*C)
  const float* src = (const float*)d_in[1];   // source (B*L*D)
  const int*   idx = (const int*)d_in[2];     // class_idx (B*L)

  float* out_fused = (float*)d_out;                      // first B*L*D
  float* out_src   = out_fused + (size_t)BB * LL * DD;   // second B*L*D

  float* cs  = (float*)d_ws;           // [B][NK][C][D] chunk sums -> prefixes
  float* tot = cs + CS_ELEMS;          // [B][C][D]

  // Decide cooperative viability once (host-only queries; graph-safe).
  static int coop_ok = -1;
  if (coop_ok < 0) {
    int dev = 0, ncu = 0, nb = 0;
    hipError_t e0 = hipGetDevice(&dev);
    hipError_t e1 = hipDeviceGetAttribute(&ncu, hipDeviceAttributeMultiprocessorCount, dev);
    hipError_t e2 = hipOccupancyMaxActiveBlocksPerMultiprocessor(&nb, fused_all, 128, 0);
    coop_ok = (e0 == hipSuccess && e1 == hipSuccess && e2 == hipSuccess &&
               nb > 0 && (long)nb * (long)ncu >= (long)(BB * NK)) ? 1 : 0;
  }

  if (coop_ok == 1) {
    void* args[] = {(void*)&src, (void*)&idx, (void*)&P, (void*)&cs,
                    (void*)&tot, (void*)&out_fused, (void*)&out_src};
    hipError_t e = hipLaunchCooperativeKernel((void*)fused_all, dim3(BB * NK),
                                              dim3(128), args, 0, stream);
    if (e == hipSuccess) return;
    coop_ok = 0;  // permanent fallback from here on
  }

  k1_chunk_sums<<<BB * NK, 256, 0, stream>>>(src, idx, cs, out_src);
  k2_scan<<<BB * CC, 128, 0, stream>>>(cs, tot);
  k4_fused<<<BB * NK, 256, 0, stream>>>(src, idx, P, cs, tot, out_fused);
}